// Round 2
// baseline (11127.630 us; speedup 1.0000x reference)
//
#include <hip/hip_runtime.h>

#define N_ENT   250002
#define DD      128
#define T_STEPS 16
#define E_EDGES 300000
#define S_SEEDS 256
#define C_NUM   50000
#define BASE    200000          // user_id_max + 1
#define ND4     (N_ENT * 32)    // float4 count of node/sums = 8,000,064

// ---------------- init: copy ent->node, zero sums/cnt/out ----------------
__global__ __launch_bounds__(256) void init_kernel(
    const float4* __restrict__ ent4, float4* __restrict__ node4,
    float4* __restrict__ sums4, float* __restrict__ cnt, float* __restrict__ out)
{
    int gid = blockIdx.x * 256 + threadIdx.x;
    if (gid < ND4) {
        node4[gid] = ent4[gid];
        sums4[gid] = make_float4(0.f, 0.f, 0.f, 0.f);
    } else if (gid < ND4 + N_ENT) {
        cnt[gid - ND4] = 0.f;
    } else if (gid == ND4 + N_ENT) {
        out[0] = 0.f;
    }
}

// ---------------- per-step: scatter msg = node[src]*rel[r] into sums[dst] ----------------
// 32 threads per edge, float4 per thread (coalesced 512B per edge row).
__global__ __launch_bounds__(256) void scatter_kernel(
    const float4* __restrict__ node4, const float4* __restrict__ rel4,
    const int* __restrict__ esrc, const int* __restrict__ edst, const int* __restrict__ erel,
    float* __restrict__ sums, float* __restrict__ cnt, int t)
{
    int gid = blockIdx.x * 256 + threadIdx.x;   // exactly E_EDGES*32 threads
    int e = gid >> 5;
    int chunk = gid & 31;
    int ebase = t * E_EDGES + e;
    int s = esrc[ebase], d = edst[ebase], r = erel[ebase];
    float4 a  = node4[s * 32 + chunk];
    float4 rv = rel4[r * 32 + chunk];
    float* sp = sums + d * DD + chunk * 4;
    atomicAdd(sp + 0, a.x * rv.x);
    atomicAdd(sp + 1, a.y * rv.y);
    atomicAdd(sp + 2, a.z * rv.z);
    atomicAdd(sp + 3, a.w * rv.w);
    if (chunk == 0) atomicAdd(cnt + d, 1.0f);
}

// ---------------- per-step: node += sums/cnt where cnt>0; re-zero sums/cnt ----------------
__global__ __launch_bounds__(256) void update_kernel(
    float4* __restrict__ node4, float4* __restrict__ sums4, float* __restrict__ cnt)
{
    int gid = blockIdx.x * 256 + threadIdx.x;
    if (gid >= ND4) return;
    int n = gid >> 5;
    int chunk = gid & 31;
    float c = cnt[n];                 // all 32 lanes of node n are in one wave:
    if (c > 0.5f) {                   // load completes before the store below -> no race
        float inv = 1.0f / c;
        float4 s4 = sums4[gid];
        float4 v  = node4[gid];
        v.x += s4.x * inv; v.y += s4.y * inv; v.z += s4.z * inv; v.w += s4.w * inv;
        node4[gid] = v;
        sums4[gid] = make_float4(0.f, 0.f, 0.f, 0.f);
        if (chunk == 0) cnt[n] = 0.f;
    }
}

// ---------------- per-step: snapshot seed rows into gathered[tt][4-j] ----------------
// After step t, snapshot feeds window slot w = 4-j of future timestep tt = t+j.
__global__ __launch_bounds__(256) void gather_kernel(
    const float4* __restrict__ node4, const int* __restrict__ seeds,
    float4* __restrict__ gath4, int t)
{
    int gid = blockIdx.x * 256 + threadIdx.x;   // 5*256*32 = 40960 threads
    int j = gid >> 13;
    int tt = t + j;
    if (tt >= T_STEPS) return;
    int rem = gid & 8191;
    int s = rem >> 5;
    int chunk = rem & 31;
    int w = 4 - j;
    int node = seeds[tt * S_SEEDS + s];
    gath4[((tt * 5 + w) * S_SEEDS + s) * 32 + chunk] = node4[node * 32 + chunk];
}

// ---------------- 5-snapshot attention per (t,s): one wave each ----------------
__global__ __launch_bounds__(64) void attn_kernel(
    const float2* __restrict__ q2, const float2* __restrict__ g2,
    const int* __restrict__ seeds, float2* __restrict__ u2)
{
    int b = blockIdx.x;          // 4096 = T*S
    int t = b >> 8;
    int s = b & 255;
    int lane = threadIdx.x;
    int seed = seeds[t * S_SEEDS + s];
    float2 q = q2[seed * 64 + lane];
    float2 g[5];
    float att[5];
    #pragma unroll
    for (int w = 0; w < 5; ++w) {
        float2 gv = g2[((t * 5 + w) * S_SEEDS + s) * 64 + lane];
        g[w] = gv;
        float p = gv.x * q.x + gv.y * q.y;
        #pragma unroll
        for (int off = 32; off > 0; off >>= 1) p += __shfl_xor(p, off, 64);
        // invalid window slots (buf zeros in reference) -> NEG mask; poison data gets weight 0
        att[w] = (w >= 4 - t) ? p : -1e9f;
    }
    float m = -1e30f;
    #pragma unroll
    for (int w = 0; w < 5; ++w) m = fmaxf(m, att[w]);
    float den = 0.f;
    #pragma unroll
    for (int w = 0; w < 5; ++w) den += __expf(att[w] - m);
    float invd = 1.0f / den;
    float2 o = make_float2(0.f, 0.f);
    #pragma unroll
    for (int w = 0; w < 5; ++w) {
        float wt = __expf(att[w] - m) * invd;
        o.x += wt * g[w].x;
        o.y += wt * g[w].y;
    }
    u2[(t * S_SEEDS + s) * 64 + lane] = o;
}

// ---------------- scores GEMM + streaming logsumexp + pos + loss ----------------
// 16 u-rows per block (in LDS, broadcast reads), 4 c-columns per thread per pass.
// |score| <= ~5 so sum(exp(score)) cannot overflow fp32: no max-subtraction needed.
__global__ __launch_bounds__(256) void score_kernel(
    const float* __restrict__ u, const float* __restrict__ ent,
    const int* __restrict__ comp_idx, float* __restrict__ out)
{
    __shared__ float u_lds[16 * DD];
    __shared__ float red[64];
    __shared__ float red2[16];
    int tid = threadIdx.x;
    int r0 = blockIdx.x * 16;

    const float4* u4 = (const float4*)(u + r0 * DD);
    float4* ul4 = (float4*)u_lds;
    ul4[tid]       = u4[tid];
    ul4[tid + 256] = u4[tid + 256];
    __syncthreads();

    float sacc[16];
    #pragma unroll
    for (int r = 0; r < 16; ++r) sacc[r] = 0.f;

    const float4* c4 = (const float4*)(ent + (size_t)BASE * DD);
    for (int cb = 0; cb < C_NUM; cb += 1024) {
        int c0 = cb + tid;
        bool v0 = (c0        < C_NUM);
        bool v1 = (c0 + 256  < C_NUM);
        bool v2 = (c0 + 512  < C_NUM);
        bool v3 = (c0 + 768  < C_NUM);
        const float4* p0 = c4 + (size_t)(v0 ? c0       : 0) * 32;
        const float4* p1 = c4 + (size_t)(v1 ? c0 + 256 : 0) * 32;
        const float4* p2 = c4 + (size_t)(v2 ? c0 + 512 : 0) * 32;
        const float4* p3 = c4 + (size_t)(v3 ? c0 + 768 : 0) * 32;

        float acc[16][4];
        #pragma unroll
        for (int r = 0; r < 16; ++r) {
            acc[r][0] = 0.f; acc[r][1] = 0.f; acc[r][2] = 0.f; acc[r][3] = 0.f;
        }
        for (int i = 0; i < 32; ++i) {
            float4 cv0 = p0[i], cv1 = p1[i], cv2 = p2[i], cv3 = p3[i];
            #pragma unroll
            for (int r = 0; r < 16; ++r) {
                float4 uv = ul4[r * 32 + i];   // wave-broadcast LDS read
                acc[r][0] += uv.x*cv0.x + uv.y*cv0.y + uv.z*cv0.z + uv.w*cv0.w;
                acc[r][1] += uv.x*cv1.x + uv.y*cv1.y + uv.z*cv1.z + uv.w*cv1.w;
                acc[r][2] += uv.x*cv2.x + uv.y*cv2.y + uv.z*cv2.z + uv.w*cv2.w;
                acc[r][3] += uv.x*cv3.x + uv.y*cv3.y + uv.z*cv3.z + uv.w*cv3.w;
            }
        }
        #pragma unroll
        for (int r = 0; r < 16; ++r) {
            if (v0) sacc[r] += __expf(acc[r][0]);
            if (v1) sacc[r] += __expf(acc[r][1]);
            if (v2) sacc[r] += __expf(acc[r][2]);
            if (v3) sacc[r] += __expf(acc[r][3]);
        }
    }

    // per-row cross-thread reduction of sum(exp)
    int wid = tid >> 6;
    #pragma unroll
    for (int r = 0; r < 16; ++r) {
        float v = sacc[r];
        #pragma unroll
        for (int off = 32; off > 0; off >>= 1) v += __shfl_xor(v, off, 64);
        if ((tid & 63) == 0) red[r * 4 + wid] = v;
    }
    __syncthreads();
    if (tid < 16) {
        int row = r0 + tid;
        float tot = red[tid*4] + red[tid*4+1] + red[tid*4+2] + red[tid*4+3];
        float lse = logf(tot);
        int ci = comp_idx[row];
        const float4* tp = (const float4*)(ent + (size_t)(BASE + ci) * DD);
        const float4* up = (const float4*)(u_lds + tid * DD);
        float pos = 0.f;
        #pragma unroll
        for (int i = 0; i < 32; ++i) {
            float4 a = up[i], bb = tp[i];
            pos += a.x*bb.x + a.y*bb.y + a.z*bb.z + a.w*bb.w;
        }
        red2[tid] = lse - pos;   // loss = sum(lse - pos)
    }
    __syncthreads();
    if (tid == 0) {
        float sl = 0.f;
        #pragma unroll
        for (int i = 0; i < 16; ++i) sl += red2[i];
        atomicAdd(out, sl);
    }
}

extern "C" void kernel_launch(void* const* d_in, const int* in_sizes, int n_in,
                              void* d_out, int out_size, void* d_ws, size_t ws_size,
                              hipStream_t stream)
{
    (void)in_sizes; (void)n_in; (void)out_size; (void)ws_size;
    const float* ent   = (const float*)d_in[0];
    const float* query = (const float*)d_in[1];
    const float* rel   = (const float*)d_in[2];
    const int* esrc    = (const int*)d_in[3];
    const int* edst    = (const int*)d_in[4];
    const int* erel    = (const int*)d_in[5];
    const int* seeds   = (const int*)d_in[6];
    const int* cidx    = (const int*)d_in[7];
    float* out = (float*)d_out;

    // workspace layout (16B aligned): node | sums | cnt | gathered | u  (~269.6 MB)
    char* ws = (char*)d_ws;
    size_t off = 0;
    float* node = (float*)(ws + off); off += (size_t)N_ENT * DD * 4;
    float* sums = (float*)(ws + off); off += (size_t)N_ENT * DD * 4;
    float* cnt  = (float*)(ws + off); off += (((size_t)N_ENT * 4) + 15) & ~(size_t)15;
    float* gath = (float*)(ws + off); off += (size_t)T_STEPS * 5 * S_SEEDS * DD * 4;
    float* u    = (float*)(ws + off); off += (size_t)T_STEPS * S_SEEDS * DD * 4;

    int init_items  = ND4 + N_ENT + 1;
    int init_blocks = (init_items + 255) / 256;
    init_kernel<<<init_blocks, 256, 0, stream>>>(
        (const float4*)ent, (float4*)node, (float4*)sums, cnt, out);

    for (int t = 0; t < T_STEPS; ++t) {
        scatter_kernel<<<E_EDGES * 32 / 256, 256, 0, stream>>>(
            (const float4*)node, (const float4*)rel, esrc, edst, erel, sums, cnt, t);
        update_kernel<<<(ND4 + 255) / 256, 256, 0, stream>>>(
            (float4*)node, (float4*)sums, cnt);
        gather_kernel<<<5 * S_SEEDS * 32 / 256, 256, 0, stream>>>(
            (const float4*)node, seeds, (float4*)gath, t);
    }
    attn_kernel<<<T_STEPS * S_SEEDS, 64, 0, stream>>>(
        (const float2*)query, (const float2*)gath, seeds, (float2*)u);
    score_kernel<<<T_STEPS * S_SEEDS / 16, 256, 0, stream>>>(u, ent, cidx, out);
}

// Round 3
// 3394.782 us; speedup vs baseline: 3.2779x; 3.2779x over previous
//
#include <hip/hip_runtime.h>

#define N_ENT   250002
#define DD      128
#define T_STEPS 16
#define E_EDGES 300000
#define S_SEEDS 256
#define C_NUM   50000
#define BASE    200000          // user_id_max + 1
#define ND4     (N_ENT * 32)    // float4 count of node = 8,000,064
#define NDS4    (N_ENT * 16)    // float4 count of bf16 sums = 4,000,032

typedef short v2s __attribute__((ext_vector_type(2)));
typedef __attribute__((ext_vector_type(8))) short short8;
typedef __attribute__((ext_vector_type(4))) float f32x4;

__device__ inline unsigned short f2bf(float f) {
    unsigned u = __float_as_uint(f);
    u += 0x7FFFu + ((u >> 16) & 1u);          // RNE
    return (unsigned short)(u >> 16);
}
__device__ inline float bf2f(unsigned short h) {
    return __uint_as_float(((unsigned)h) << 16);
}
__device__ inline void pk_add_bf16(unsigned short* addr, float x, float y) {
#if __has_builtin(__builtin_amdgcn_global_atomic_fadd_v2bf16)
    v2s v;
    v.x = (short)f2bf(x); v.y = (short)f2bf(y);
    __builtin_amdgcn_global_atomic_fadd_v2bf16((__attribute__((address_space(1))) v2s*)addr, v);
#else
    unsigned packed = (unsigned)f2bf(x) | ((unsigned)f2bf(y) << 16);
    asm volatile("global_atomic_pk_add_bf16 %0, %1, off" :: "v"(addr), "v"(packed) : "memory");
#endif
}

// ---------------- init: copy ent->node, zero sums(bf16)/cnt/rowsum/out ----------------
__global__ __launch_bounds__(256) void init_kernel(
    const float4* __restrict__ ent4, float4* __restrict__ node4,
    float4* __restrict__ sums4, float* __restrict__ cnt,
    float* __restrict__ rowsum, float* __restrict__ out)
{
    int gid = blockIdx.x * 256 + threadIdx.x;
    if (gid < ND4) {
        node4[gid] = ent4[gid];
    } else if (gid < ND4 + NDS4) {
        sums4[gid - ND4] = make_float4(0.f, 0.f, 0.f, 0.f);
    } else if (gid < ND4 + NDS4 + N_ENT) {
        cnt[gid - ND4 - NDS4] = 0.f;
    } else if (gid < ND4 + NDS4 + N_ENT + T_STEPS * S_SEEDS) {
        rowsum[gid - ND4 - NDS4 - N_ENT] = 0.f;
    } else if (gid == ND4 + NDS4 + N_ENT + T_STEPS * S_SEEDS) {
        out[0] = 0.f;
    }
}

// ---------------- convert all_c to bf16 once per launch ----------------
__global__ __launch_bounds__(256) void conv_kernel(
    const float4* __restrict__ c4, ushort4* __restrict__ cb4)
{
    int gid = blockIdx.x * 256 + threadIdx.x;    // C_NUM*128/4 = 1,600,000
    float4 v = c4[gid];
    cb4[gid] = make_ushort4(f2bf(v.x), f2bf(v.y), f2bf(v.z), f2bf(v.w));
}

// ---------------- per-step: scatter msg = node[src]*rel[r] into bf16 sums[dst] ----------------
__global__ __launch_bounds__(256) void scatter_kernel(
    const float4* __restrict__ node4, const float4* __restrict__ rel4,
    const int* __restrict__ esrc, const int* __restrict__ edst, const int* __restrict__ erel,
    unsigned short* __restrict__ sums, float* __restrict__ cnt, int t)
{
    int gid = blockIdx.x * 256 + threadIdx.x;   // exactly E_EDGES*32 threads
    int e = gid >> 5;
    int chunk = gid & 31;
    int ebase = t * E_EDGES + e;
    int s = esrc[ebase], d = edst[ebase], r = erel[ebase];
    float4 a  = node4[s * 32 + chunk];
    float4 rv = rel4[r * 32 + chunk];
    unsigned short* sp = sums + (size_t)d * DD + chunk * 4;
    pk_add_bf16(sp,     a.x * rv.x, a.y * rv.y);
    pk_add_bf16(sp + 2, a.z * rv.z, a.w * rv.w);
    if (chunk == 0) atomicAdd(cnt + d, 1.0f);
}

// ---------------- per-step: node += sums/cnt where cnt>0; re-zero sums/cnt ----------------
__global__ __launch_bounds__(256) void update_kernel(
    float4* __restrict__ node4, unsigned short* __restrict__ sums, float* __restrict__ cnt)
{
    int gid = blockIdx.x * 256 + threadIdx.x;
    if (gid >= ND4) return;
    int n = gid >> 5;
    int chunk = gid & 31;
    float c = cnt[n];                 // all 32 lanes of node n are in one wave
    if (c > 0.5f) {
        float inv = 1.0f / c;
        unsigned short* sp = sums + (size_t)n * DD + chunk * 4;
        ushort4 s4 = *(const ushort4*)sp;
        float4 v  = node4[gid];
        v.x += bf2f(s4.x) * inv; v.y += bf2f(s4.y) * inv;
        v.z += bf2f(s4.z) * inv; v.w += bf2f(s4.w) * inv;
        node4[gid] = v;
        *(ushort4*)sp = make_ushort4(0, 0, 0, 0);
        if (chunk == 0) cnt[n] = 0.f;
    }
}

// ---------------- per-step: snapshot seed rows into gathered[tt][4-j] ----------------
__global__ __launch_bounds__(256) void gather_kernel(
    const float4* __restrict__ node4, const int* __restrict__ seeds,
    float4* __restrict__ gath4, int t)
{
    int gid = blockIdx.x * 256 + threadIdx.x;   // 5*256*32 = 40960 threads
    int j = gid >> 13;
    int tt = t + j;
    if (tt >= T_STEPS) return;
    int rem = gid & 8191;
    int s = rem >> 5;
    int chunk = rem & 31;
    int w = 4 - j;
    int node = seeds[tt * S_SEEDS + s];
    gath4[((tt * 5 + w) * S_SEEDS + s) * 32 + chunk] = node4[node * 32 + chunk];
}

// ---------------- 5-snapshot attention per (t,s): one wave each; writes u fp32 + bf16 ----------------
__global__ __launch_bounds__(64) void attn_kernel(
    const float2* __restrict__ q2, const float2* __restrict__ g2,
    const int* __restrict__ seeds, float2* __restrict__ u2, unsigned* __restrict__ ubf)
{
    int b = blockIdx.x;          // 4096 = T*S
    int t = b >> 8;
    int s = b & 255;
    int lane = threadIdx.x;
    int seed = seeds[t * S_SEEDS + s];
    float2 q = q2[seed * 64 + lane];
    float2 g[5];
    float att[5];
    #pragma unroll
    for (int w = 0; w < 5; ++w) {
        float2 gv = g2[((t * 5 + w) * S_SEEDS + s) * 64 + lane];
        g[w] = gv;
        float p = gv.x * q.x + gv.y * q.y;
        #pragma unroll
        for (int off = 32; off > 0; off >>= 1) p += __shfl_xor(p, off, 64);
        att[w] = (w >= 4 - t) ? p : -1e9f;   // invalid slots masked -> weight exactly 0
    }
    float m = -1e30f;
    #pragma unroll
    for (int w = 0; w < 5; ++w) m = fmaxf(m, att[w]);
    float den = 0.f;
    #pragma unroll
    for (int w = 0; w < 5; ++w) den += __expf(att[w] - m);
    float invd = 1.0f / den;
    float2 o = make_float2(0.f, 0.f);
    #pragma unroll
    for (int w = 0; w < 5; ++w) {
        float wt = __expf(att[w] - m) * invd;
        o.x += wt * g[w].x;
        o.y += wt * g[w].y;
    }
    int idx = (t * S_SEEDS + s) * 64 + lane;
    u2[idx] = o;
    ubf[idx] = (unsigned)f2bf(o.x) | ((unsigned)f2bf(o.y) << 16);
}

// ---------------- MFMA score GEMM + streaming sum(exp) ----------------
// Block = 4 waves, 64 rows (4 groups of 16). Wave slice j = by*4+w streams col-chunks
// j, j+32, ... of 3125. A-frags register-resident; B read from bf16 all_c (L3-resident).
// |score| < ~1 so sum(exp) cannot overflow fp32: no max subtraction.
__global__ __launch_bounds__(256) void score_mfma(
    const unsigned short* __restrict__ ub, const unsigned short* __restrict__ cb,
    float* __restrict__ rowsum)
{
    int tid = threadIdx.x;
    int wv = tid >> 6, lane = tid & 63;
    int col16 = lane & 15, quad = lane >> 4;
    int rb = blockIdx.x;                 // 64 row-blocks of 64 rows
    int j = blockIdx.y * 4 + wv;         // wave slice 0..31

    short8 a[4][4];
    #pragma unroll
    for (int g = 0; g < 4; ++g) {
        const unsigned short* ap = ub + (size_t)(rb * 64 + g * 16 + col16) * DD + quad * 8;
        #pragma unroll
        for (int kk = 0; kk < 4; ++kk)
            a[g][kk] = *(const short8*)(ap + kk * 32);
    }

    float es[4][4];
    #pragma unroll
    for (int g = 0; g < 4; ++g)
        #pragma unroll
        for (int r = 0; r < 4; ++r) es[g][r] = 0.f;

    for (int c = j; c < 3125; c += 32) {
        const unsigned short* bp = cb + (size_t)(c * 16 + col16) * DD + quad * 8;
        short8 b0 = *(const short8*)(bp);
        short8 b1 = *(const short8*)(bp + 32);
        short8 b2 = *(const short8*)(bp + 64);
        short8 b3 = *(const short8*)(bp + 96);
        #pragma unroll
        for (int g = 0; g < 4; ++g) {
            f32x4 d = {0.f, 0.f, 0.f, 0.f};
            d = __builtin_amdgcn_mfma_f32_16x16x32_bf16(a[g][0], b0, d, 0, 0, 0);
            d = __builtin_amdgcn_mfma_f32_16x16x32_bf16(a[g][1], b1, d, 0, 0, 0);
            d = __builtin_amdgcn_mfma_f32_16x16x32_bf16(a[g][2], b2, d, 0, 0, 0);
            d = __builtin_amdgcn_mfma_f32_16x16x32_bf16(a[g][3], b3, d, 0, 0, 0);
            #pragma unroll
            for (int r = 0; r < 4; ++r) es[g][r] += __expf(d[r]);
        }
    }

    // sum over the 16 cols held by lanes sharing `quad`; C/D row = quad*4+r
    #pragma unroll
    for (int g = 0; g < 4; ++g) {
        #pragma unroll
        for (int r = 0; r < 4; ++r) {
            float v = es[g][r];
            v += __shfl_xor(v, 1, 64);
            v += __shfl_xor(v, 2, 64);
            v += __shfl_xor(v, 4, 64);
            v += __shfl_xor(v, 8, 64);
            if (col16 == 0)
                atomicAdd(&rowsum[rb * 64 + g * 16 + quad * 4 + r], v);
        }
    }
}

// ---------------- final: loss = sum(log(rowsum) - pos), pos in fp32 ----------------
__global__ __launch_bounds__(256) void final_kernel(
    const float2* __restrict__ u2, const float* __restrict__ ent,
    const int* __restrict__ cidx, const float* __restrict__ rowsum,
    float* __restrict__ out)
{
    int wv = threadIdx.x >> 6, lane = threadIdx.x & 63;
    int row = blockIdx.x * 4 + wv;       // grid 1024 -> 4096 rows
    int ci = cidx[row];
    const float2* tp = (const float2*)(ent + (size_t)(BASE + ci) * DD);
    float2 a = u2[row * 64 + lane];
    float2 t = tp[lane];
    float p = a.x * t.x + a.y * t.y;
    #pragma unroll
    for (int off = 32; off > 0; off >>= 1) p += __shfl_xor(p, off, 64);
    if (lane == 0) atomicAdd(out, logf(rowsum[row]) - p);
}

extern "C" void kernel_launch(void* const* d_in, const int* in_sizes, int n_in,
                              void* d_out, int out_size, void* d_ws, size_t ws_size,
                              hipStream_t stream)
{
    (void)in_sizes; (void)n_in; (void)out_size; (void)ws_size;
    const float* ent   = (const float*)d_in[0];
    const float* query = (const float*)d_in[1];
    const float* rel   = (const float*)d_in[2];
    const int* esrc    = (const int*)d_in[3];
    const int* edst    = (const int*)d_in[4];
    const int* erel    = (const int*)d_in[5];
    const int* seeds   = (const int*)d_in[6];
    const int* cidx    = (const int*)d_in[7];
    float* out = (float*)d_out;

    // ws layout (16B aligned): node | sums(bf16) | cnt | gath | u | ubf | cb | rowsum  (~220 MB)
    char* ws = (char*)d_ws;
    size_t off = 0;
    float*          node = (float*)(ws + off);          off += (size_t)N_ENT * DD * 4;
    unsigned short* sums = (unsigned short*)(ws + off); off += (size_t)N_ENT * DD * 2;
    float*          cnt  = (float*)(ws + off);          off += (((size_t)N_ENT * 4) + 15) & ~(size_t)15;
    float*          gath = (float*)(ws + off);          off += (size_t)T_STEPS * 5 * S_SEEDS * DD * 4;
    float*          u    = (float*)(ws + off);          off += (size_t)T_STEPS * S_SEEDS * DD * 4;
    unsigned short* ubf  = (unsigned short*)(ws + off); off += (size_t)T_STEPS * S_SEEDS * DD * 2;
    unsigned short* cb   = (unsigned short*)(ws + off); off += (size_t)C_NUM * DD * 2;
    float*          rsum = (float*)(ws + off);          off += (size_t)T_STEPS * S_SEEDS * 4;

    int init_items  = ND4 + NDS4 + N_ENT + T_STEPS * S_SEEDS + 1;
    init_kernel<<<(init_items + 255) / 256, 256, 0, stream>>>(
        (const float4*)ent, (float4*)node, (float4*)sums, cnt, rsum, out);
    conv_kernel<<<C_NUM * DD / 4 / 256, 256, 0, stream>>>(
        (const float4*)(ent + (size_t)BASE * DD), (ushort4*)cb);

    for (int t = 0; t < T_STEPS; ++t) {
        scatter_kernel<<<E_EDGES * 32 / 256, 256, 0, stream>>>(
            (const float4*)node, (const float4*)rel, esrc, edst, erel, sums, cnt, t);
        update_kernel<<<(ND4 + 255) / 256, 256, 0, stream>>>(
            (float4*)node, sums, cnt);
        gather_kernel<<<5 * S_SEEDS * 32 / 256, 256, 0, stream>>>(
            (const float4*)node, seeds, (float4*)gath, t);
    }
    attn_kernel<<<T_STEPS * S_SEEDS, 64, 0, stream>>>(
        (const float2*)query, (const float2*)gath, seeds, (float2*)u, (unsigned*)ubf);
    score_mfma<<<dim3(64, 8), 256, 0, stream>>>(ubf, cb, rsum);
    final_kernel<<<T_STEPS * S_SEEDS / 4, 256, 0, stream>>>(
        (const float2*)u, ent, cidx, rsum, out);
}

// Round 4
// 2925.670 us; speedup vs baseline: 3.8034x; 1.1603x over previous
//
#include <hip/hip_runtime.h>

#define N_ENT   250002
#define DD      128
#define T_STEPS 16
#define E_EDGES 300000
#define S_SEEDS 256
#define C_NUM   50000
#define BASE    200000          // user_id_max + 1

typedef __attribute__((ext_vector_type(8))) short short8;
typedef __attribute__((ext_vector_type(4))) float f32x4;

__device__ inline unsigned short f2bf(float f) {
    unsigned u = __float_as_uint(f);
    u += 0x7FFFu + ((u >> 16) & 1u);          // RNE
    return (unsigned short)(u >> 16);
}
__device__ inline float bf_lo(unsigned p) { return __uint_as_float(p << 16); }
__device__ inline float bf_hi(unsigned p) { return __uint_as_float(p & 0xffff0000u); }
__device__ inline unsigned pk2(float x, float y) {
    return (unsigned)f2bf(x) | ((unsigned)f2bf(y) << 16);
}

// ---------------- init: node_bf <- bf16(ent); zero offs/rowsum/out ----------------
#define NODE_W (N_ENT * 64)          // 16,000,128 unsigned (2 bf16 each)
#define OFFS_W (T_STEPS * N_ENT)     //  4,000,032 ints
__global__ __launch_bounds__(256) void init_kernel(
    const float2* __restrict__ ent2, unsigned* __restrict__ node_bf,
    int* __restrict__ offs, float* __restrict__ rowsum, float* __restrict__ out)
{
    int gid = blockIdx.x * 256 + threadIdx.x;
    if (gid < NODE_W) {
        float2 v = ent2[gid];
        node_bf[gid] = pk2(v.x, v.y);
    } else if (gid < NODE_W + OFFS_W) {
        offs[gid - NODE_W] = 0;
    } else if (gid < NODE_W + OFFS_W + T_STEPS * S_SEEDS) {
        rowsum[gid - NODE_W - OFFS_W] = 0.f;
    } else if (gid == NODE_W + OFFS_W + T_STEPS * S_SEEDS) {
        out[0] = 0.f;
    }
}

// ---------------- convert all_c to bf16 (from pristine ent) ----------------
__global__ __launch_bounds__(256) void conv_kernel(
    const float4* __restrict__ c4, ushort4* __restrict__ cb4)
{
    int gid = blockIdx.x * 256 + threadIdx.x;    // C_NUM*128/4 = 1,600,000
    float4 v = c4[gid];
    cb4[gid] = make_ushort4(f2bf(v.x), f2bf(v.y), f2bf(v.z), f2bf(v.w));
}

// ---------------- CSR build 1: per-step degree histogram ----------------
__global__ __launch_bounds__(256) void hist_kernel(
    const int* __restrict__ edst, int* __restrict__ offs)
{
    int e = blockIdx.x * 256 + threadIdx.x;
    int t = blockIdx.y;
    if (e >= E_EDGES) return;
    atomicAdd(&offs[t * N_ENT + edst[t * E_EDGES + e]], 1);
}

// ---------------- CSR build 2: in-place exclusive scan per step (1 block/step) ----------------
__global__ __launch_bounds__(1024) void scan_kernel(int* __restrict__ offs)
{
    __shared__ int sc[1024];
    int t = blockIdx.x;
    int tid = threadIdx.x;
    int* p = offs + t * N_ENT;
    const int CH = (N_ENT + 1023) / 1024;    // 245
    int lo = tid * CH;
    int hi = min(lo + CH, N_ENT);
    int local = 0;
    for (int i = lo; i < hi; ++i) local += p[i];
    sc[tid] = local;
    __syncthreads();
    for (int off = 1; off < 1024; off <<= 1) {
        int v = (tid >= off) ? sc[tid - off] : 0;
        __syncthreads();
        sc[tid] += v;
        __syncthreads();
    }
    int running = (tid > 0) ? sc[tid - 1] : 0;   // exclusive prefix
    for (int i = lo; i < hi; ++i) {
        int v = p[i];
        p[i] = running;
        running += v;
    }
}

// ---------------- CSR build 3: scatter (src,rel) pairs; offs becomes END offsets ----------------
__global__ __launch_bounds__(256) void scatp_kernel(
    const int* __restrict__ esrc, const int* __restrict__ edst, const int* __restrict__ erel,
    int* __restrict__ offs, int2* __restrict__ sortedp)
{
    int e = blockIdx.x * 256 + threadIdx.x;
    int t = blockIdx.y;
    if (e >= E_EDGES) return;
    int eb = t * E_EDGES + e;
    int d = edst[eb];
    int pos = atomicAdd(&offs[t * N_ENT + d], 1);
    sortedp[(size_t)t * E_EDGES + pos] = make_int2(esrc[eb], erel[eb]);
}

// ---------------- per-step: mean message per active node (no atomics) ----------------
// One wave per dst node; lane holds dims (2l, 2l+1). start = offs[n-1] (ends array).
__global__ __launch_bounds__(256) void gather_msg(
    const unsigned* __restrict__ node_bf, const float2* __restrict__ rel2,
    const int* __restrict__ offs, const int2* __restrict__ sortedp,
    unsigned* __restrict__ meanbf, int t)
{
    int n = blockIdx.x * 4 + (threadIdx.x >> 6);
    int lane = threadIdx.x & 63;
    if (n >= N_ENT) return;
    const int* op = offs + t * N_ENT;
    int end = op[n];
    int start = (n > 0) ? op[n - 1] : 0;
    int deg = end - start;
    if (deg == 0) return;
    const int2* sp = sortedp + (size_t)t * E_EDGES;
    float ax = 0.f, ay = 0.f;
    for (int p = start; p < end; ++p) {
        int2 pr = sp[p];
        unsigned nb = node_bf[(size_t)pr.x * 64 + lane];
        float2 rv = rel2[pr.y * 64 + lane];
        ax += bf_lo(nb) * rv.x;
        ay += bf_hi(nb) * rv.y;
    }
    float inv = 1.0f / (float)deg;
    meanbf[(size_t)n * 64 + lane] = pk2(ax * inv, ay * inv);
}

// ---------------- per-step: node += mean for active nodes only ----------------
__global__ __launch_bounds__(256) void update_kernel(
    unsigned* __restrict__ node_bf, const unsigned* __restrict__ meanbf,
    const int* __restrict__ offs, int t)
{
    int n = blockIdx.x * 4 + (threadIdx.x >> 6);
    int lane = threadIdx.x & 63;
    if (n >= N_ENT) return;
    const int* op = offs + t * N_ENT;
    int end = op[n];
    int start = (n > 0) ? op[n - 1] : 0;
    if (end == start) return;
    size_t idx = (size_t)n * 64 + lane;
    unsigned nb = node_bf[idx];
    unsigned mb = meanbf[idx];
    node_bf[idx] = pk2(bf_lo(nb) + bf_lo(mb), bf_hi(nb) + bf_hi(mb));
}

// ---------------- per-step: snapshot seed rows into gathered[tt][4-j] (fp32) ----------------
__global__ __launch_bounds__(256) void gather_seed(
    const unsigned* __restrict__ node_bf, const int* __restrict__ seeds,
    float2* __restrict__ gath2, int t)
{
    int gid = blockIdx.x * 256 + threadIdx.x;   // 5*256*64 = 81920 threads
    int j = gid >> 14;
    int tt = t + j;
    if (tt >= T_STEPS) return;
    int rem = gid & 16383;
    int s = rem >> 6;
    int lane = rem & 63;
    int w = 4 - j;
    int node = seeds[tt * S_SEEDS + s];
    unsigned nb = node_bf[(size_t)node * 64 + lane];
    gath2[((tt * 5 + w) * S_SEEDS + s) * 64 + lane] = make_float2(bf_lo(nb), bf_hi(nb));
}

// ---------------- 5-snapshot attention per (t,s): one wave each; writes u fp32 + bf16 ----------------
__global__ __launch_bounds__(64) void attn_kernel(
    const float2* __restrict__ q2, const float2* __restrict__ g2,
    const int* __restrict__ seeds, float2* __restrict__ u2, unsigned* __restrict__ ubf)
{
    int b = blockIdx.x;          // 4096 = T*S
    int t = b >> 8;
    int s = b & 255;
    int lane = threadIdx.x;
    int seed = seeds[t * S_SEEDS + s];
    float2 q = q2[seed * 64 + lane];
    float2 g[5];
    float att[5];
    #pragma unroll
    for (int w = 0; w < 5; ++w) {
        float2 gv = g2[((t * 5 + w) * S_SEEDS + s) * 64 + lane];
        g[w] = gv;
        float p = gv.x * q.x + gv.y * q.y;
        #pragma unroll
        for (int off = 32; off > 0; off >>= 1) p += __shfl_xor(p, off, 64);
        att[w] = (w >= 4 - t) ? p : -1e9f;   // invalid slots masked -> weight exactly 0
    }
    float m = -1e30f;
    #pragma unroll
    for (int w = 0; w < 5; ++w) m = fmaxf(m, att[w]);
    float den = 0.f;
    #pragma unroll
    for (int w = 0; w < 5; ++w) den += __expf(att[w] - m);
    float invd = 1.0f / den;
    float2 o = make_float2(0.f, 0.f);
    #pragma unroll
    for (int w = 0; w < 5; ++w) {
        float wt = __expf(att[w] - m) * invd;
        o.x += wt * g[w].x;
        o.y += wt * g[w].y;
    }
    int idx = (t * S_SEEDS + s) * 64 + lane;
    u2[idx] = o;
    ubf[idx] = pk2(o.x, o.y);
}

// ---------------- MFMA score GEMM + streaming sum(exp) ----------------
__global__ __launch_bounds__(256) void score_mfma(
    const unsigned short* __restrict__ ub, const unsigned short* __restrict__ cb,
    float* __restrict__ rowsum)
{
    int tid = threadIdx.x;
    int wv = tid >> 6, lane = tid & 63;
    int col16 = lane & 15, quad = lane >> 4;
    int rb = blockIdx.x;                 // 64 row-blocks of 64 rows
    int j = blockIdx.y * 4 + wv;         // wave slice 0..31

    short8 a[4][4];
    #pragma unroll
    for (int g = 0; g < 4; ++g) {
        const unsigned short* ap = ub + (size_t)(rb * 64 + g * 16 + col16) * DD + quad * 8;
        #pragma unroll
        for (int kk = 0; kk < 4; ++kk)
            a[g][kk] = *(const short8*)(ap + kk * 32);
    }

    float es[4][4];
    #pragma unroll
    for (int g = 0; g < 4; ++g)
        #pragma unroll
        for (int r = 0; r < 4; ++r) es[g][r] = 0.f;

    for (int c = j; c < 3125; c += 32) {
        const unsigned short* bp = cb + (size_t)(c * 16 + col16) * DD + quad * 8;
        short8 b0 = *(const short8*)(bp);
        short8 b1 = *(const short8*)(bp + 32);
        short8 b2 = *(const short8*)(bp + 64);
        short8 b3 = *(const short8*)(bp + 96);
        #pragma unroll
        for (int g = 0; g < 4; ++g) {
            f32x4 d = {0.f, 0.f, 0.f, 0.f};
            d = __builtin_amdgcn_mfma_f32_16x16x32_bf16(a[g][0], b0, d, 0, 0, 0);
            d = __builtin_amdgcn_mfma_f32_16x16x32_bf16(a[g][1], b1, d, 0, 0, 0);
            d = __builtin_amdgcn_mfma_f32_16x16x32_bf16(a[g][2], b2, d, 0, 0, 0);
            d = __builtin_amdgcn_mfma_f32_16x16x32_bf16(a[g][3], b3, d, 0, 0, 0);
            #pragma unroll
            for (int r = 0; r < 4; ++r) es[g][r] += __expf(d[r]);
        }
    }

    #pragma unroll
    for (int g = 0; g < 4; ++g) {
        #pragma unroll
        for (int r = 0; r < 4; ++r) {
            float v = es[g][r];
            v += __shfl_xor(v, 1, 64);
            v += __shfl_xor(v, 2, 64);
            v += __shfl_xor(v, 4, 64);
            v += __shfl_xor(v, 8, 64);
            if (col16 == 0)
                atomicAdd(&rowsum[rb * 64 + g * 16 + quad * 4 + r], v);
        }
    }
}

// ---------------- final: loss = sum(log(rowsum) - pos), pos in fp32 ----------------
__global__ __launch_bounds__(256) void final_kernel(
    const float2* __restrict__ u2, const float* __restrict__ ent,
    const int* __restrict__ cidx, const float* __restrict__ rowsum,
    float* __restrict__ out)
{
    int wv = threadIdx.x >> 6, lane = threadIdx.x & 63;
    int row = blockIdx.x * 4 + wv;       // grid 1024 -> 4096 rows
    int ci = cidx[row];
    const float2* tp = (const float2*)(ent + (size_t)(BASE + ci) * DD);
    float2 a = u2[row * 64 + lane];
    float2 t = tp[lane];
    float p = a.x * t.x + a.y * t.y;
    #pragma unroll
    for (int off = 32; off > 0; off >>= 1) p += __shfl_xor(p, off, 64);
    if (lane == 0) atomicAdd(out, logf(rowsum[row]) - p);
}

extern "C" void kernel_launch(void* const* d_in, const int* in_sizes, int n_in,
                              void* d_out, int out_size, void* d_ws, size_t ws_size,
                              hipStream_t stream)
{
    (void)in_sizes; (void)n_in; (void)out_size; (void)ws_size;
    const float* ent   = (const float*)d_in[0];
    const float* query = (const float*)d_in[1];
    const float* rel   = (const float*)d_in[2];
    const int* esrc    = (const int*)d_in[3];
    const int* edst    = (const int*)d_in[4];
    const int* erel    = (const int*)d_in[5];
    const int* seeds   = (const int*)d_in[6];
    const int* cidx    = (const int*)d_in[7];
    float* out = (float*)d_out;

    // ws layout (16B-aligned sizes): node_bf | meanbf | offs | sortedp | gath | u | ubf | cb | rowsum  (~209 MB)
    char* ws = (char*)d_ws;
    size_t off = 0;
    unsigned* node_bf = (unsigned*)(ws + off);       off += (size_t)N_ENT * DD * 2;          // 64.0 MB
    unsigned* meanbf  = (unsigned*)(ws + off);       off += (size_t)N_ENT * DD * 2;          // 64.0 MB
    int*      offs    = (int*)(ws + off);            off += (size_t)T_STEPS * N_ENT * 4;     // 16.0 MB
    int2*     sortedp = (int2*)(ws + off);           off += (size_t)T_STEPS * E_EDGES * 8;   // 38.4 MB
    float*    gath    = (float*)(ws + off);          off += (size_t)T_STEPS * 5 * S_SEEDS * DD * 4;
    float*    u       = (float*)(ws + off);          off += (size_t)T_STEPS * S_SEEDS * DD * 4;
    unsigned* ubf     = (unsigned*)(ws + off);       off += (size_t)T_STEPS * S_SEEDS * DD * 2;
    unsigned short* cb = (unsigned short*)(ws + off); off += (size_t)C_NUM * DD * 2;
    float*    rsum    = (float*)(ws + off);          off += (size_t)T_STEPS * S_SEEDS * 4;

    int init_items = NODE_W + OFFS_W + T_STEPS * S_SEEDS + 1;
    init_kernel<<<(init_items + 255) / 256, 256, 0, stream>>>(
        (const float2*)ent, node_bf, offs, rsum, out);
    conv_kernel<<<C_NUM * DD / 4 / 256, 256, 0, stream>>>(
        (const float4*)(ent + (size_t)BASE * DD), (ushort4*)cb);

    dim3 egrid((E_EDGES + 255) / 256, T_STEPS);
    hist_kernel<<<egrid, 256, 0, stream>>>(edst, offs);
    scan_kernel<<<T_STEPS, 1024, 0, stream>>>(offs);
    scatp_kernel<<<egrid, 256, 0, stream>>>(esrc, edst, erel, offs, sortedp);

    int ngrid = (N_ENT + 3) / 4;
    for (int t = 0; t < T_STEPS; ++t) {
        gather_msg<<<ngrid, 256, 0, stream>>>(
            node_bf, (const float2*)rel, offs, sortedp, meanbf, t);
        update_kernel<<<ngrid, 256, 0, stream>>>(node_bf, meanbf, offs, t);
        gather_seed<<<5 * S_SEEDS * 64 / 256, 256, 0, stream>>>(
            node_bf, seeds, (float2*)gath, t);
    }
    attn_kernel<<<T_STEPS * S_SEEDS, 64, 0, stream>>>(
        (const float2*)query, (const float2*)gath, seeds, (float2*)u, (unsigned*)ubf);
    score_mfma<<<dim3(64, 8), 256, 0, stream>>>((const unsigned short*)ubf, cb, rsum);
    final_kernel<<<T_STEPS * S_SEEDS / 4, 256, 0, stream>>>(
        (const float2*)u, ent, cidx, rsum, out);
}

// Round 5
// 2512.385 us; speedup vs baseline: 4.4291x; 1.1645x over previous
//
#include <hip/hip_runtime.h>

#define N_ENT   250002
#define DD      128
#define T_STEPS 16
#define E_EDGES 300000
#define S_SEEDS 256
#define C_NUM   50000
#define BASE    200000          // user_id_max + 1
#define NB      245             // scan blocks per step (245*1024 = 250880 >= N_ENT)
#define N_PAD   (NB * 1024)     // padded per-step offs row

typedef __attribute__((ext_vector_type(8))) short short8;
typedef __attribute__((ext_vector_type(4))) float f32x4;

__device__ inline unsigned short f2bf(float f) {
    unsigned u = __float_as_uint(f);
    u += 0x7FFFu + ((u >> 16) & 1u);          // RNE
    return (unsigned short)(u >> 16);
}
__device__ inline float bf_lo(unsigned p) { return __uint_as_float(p << 16); }
__device__ inline float bf_hi(unsigned p) { return __uint_as_float(p & 0xffff0000u); }
__device__ inline unsigned pk2(float x, float y) {
    return (unsigned)f2bf(x) | ((unsigned)f2bf(y) << 16);
}

// ---------------- init: node_bf <- bf16(ent); zero offs(padded)/rowsum/out ----------------
#define NODE_W (N_ENT * 64)          // 16,000,128 unsigned (2 bf16 each)
#define OFFS_W (T_STEPS * N_PAD)     //  4,014,080 ints (padding included)
__global__ __launch_bounds__(256) void init_kernel(
    const float2* __restrict__ ent2, unsigned* __restrict__ node_bf,
    int* __restrict__ offs, float* __restrict__ rowsum, float* __restrict__ out)
{
    int gid = blockIdx.x * 256 + threadIdx.x;
    if (gid < NODE_W) {
        float2 v = ent2[gid];
        node_bf[gid] = pk2(v.x, v.y);
    } else if (gid < NODE_W + OFFS_W) {
        offs[gid - NODE_W] = 0;
    } else if (gid < NODE_W + OFFS_W + T_STEPS * S_SEEDS) {
        rowsum[gid - NODE_W - OFFS_W] = 0.f;
    } else if (gid == NODE_W + OFFS_W + T_STEPS * S_SEEDS) {
        out[0] = 0.f;
    }
}

// ---------------- convert all_c to bf16 (from pristine ent) ----------------
__global__ __launch_bounds__(256) void conv_kernel(
    const float4* __restrict__ c4, ushort4* __restrict__ cb4)
{
    int gid = blockIdx.x * 256 + threadIdx.x;    // C_NUM*128/4 = 1,600,000
    float4 v = c4[gid];
    cb4[gid] = make_ushort4(f2bf(v.x), f2bf(v.y), f2bf(v.z), f2bf(v.w));
}

// ---------------- CSR build 1: per-step degree histogram ----------------
__global__ __launch_bounds__(256) void hist_kernel(
    const int* __restrict__ edst, int* __restrict__ offs)
{
    int e = blockIdx.x * 256 + threadIdx.x;
    int t = blockIdx.y;
    if (e >= E_EDGES) return;
    atomicAdd(&offs[t * N_PAD + edst[t * E_EDGES + e]], 1);
}

// ---------------- CSR build 2a: per-block partial sums ----------------
__global__ __launch_bounds__(256) void scanA_kernel(
    const int* __restrict__ offs, int* __restrict__ partials)
{
    int t = blockIdx.y, b = blockIdx.x, tid = threadIdx.x;
    const int4 v = *(const int4*)(offs + (size_t)t * N_PAD + b * 1024 + tid * 4);
    int s = v.x + v.y + v.z + v.w;
    #pragma unroll
    for (int off = 32; off > 0; off >>= 1) s += __shfl_xor(s, off, 64);
    __shared__ int wsum[4];
    int lane = tid & 63, wv = tid >> 6;
    if (lane == 0) wsum[wv] = s;
    __syncthreads();
    if (tid == 0) partials[t * NB + b] = wsum[0] + wsum[1] + wsum[2] + wsum[3];
}

// ---------------- CSR build 2b: exclusive scan of partials per step ----------------
__global__ __launch_bounds__(256) void scanB_kernel(int* __restrict__ partials)
{
    __shared__ int sc[256];
    int t = blockIdx.x, tid = threadIdx.x;
    int v = (tid < NB) ? partials[t * NB + tid] : 0;
    sc[tid] = v;
    __syncthreads();
    for (int off = 1; off < 256; off <<= 1) {
        int y = (tid >= off) ? sc[tid - off] : 0;
        __syncthreads();
        sc[tid] += y;
        __syncthreads();
    }
    if (tid < NB) partials[t * NB + tid] = (tid > 0) ? sc[tid - 1] : 0;
}

// ---------------- CSR build 2c: block-local exclusive scan + block prefix ----------------
__global__ __launch_bounds__(256) void scanC_kernel(
    int* __restrict__ offs, const int* __restrict__ partials)
{
    int t = blockIdx.y, b = blockIdx.x, tid = threadIdx.x;
    int* base = offs + (size_t)t * N_PAD + b * 1024 + tid * 4;
    int4 v = *(const int4*)base;
    int s = v.x + v.y + v.z + v.w;
    int lane = tid & 63, wv = tid >> 6;
    int x = s;                               // inclusive wave scan
    #pragma unroll
    for (int off = 1; off < 64; off <<= 1) {
        int y = __shfl_up(x, off, 64);
        if (lane >= off) x += y;
    }
    __shared__ int wsum[4];
    if (lane == 63) wsum[wv] = x;
    __syncthreads();
    int prefix = partials[t * NB + b];
    for (int w = 0; w < 4; ++w) prefix += (w < wv) ? wsum[w] : 0;
    int excl = prefix + x - s;               // exclusive of this thread's 4 elems
    int4 o;
    o.x = excl; o.y = o.x + v.x; o.z = o.y + v.y; o.w = o.z + v.z;
    *(int4*)base = o;
}

// ---------------- CSR build 3: scatter (src,rel) pairs; offs becomes END offsets ----------------
__global__ __launch_bounds__(256) void scatp_kernel(
    const int* __restrict__ esrc, const int* __restrict__ edst, const int* __restrict__ erel,
    int* __restrict__ offs, int2* __restrict__ sortedp)
{
    int e = blockIdx.x * 256 + threadIdx.x;
    int t = blockIdx.y;
    if (e >= E_EDGES) return;
    int eb = t * E_EDGES + e;
    int d = edst[eb];
    int pos = atomicAdd(&offs[t * N_PAD + d], 1);
    sortedp[(size_t)t * E_EDGES + pos] = make_int2(esrc[eb], erel[eb]);
}

// ---------------- per-step: mean message per active node (no atomics) ----------------
__global__ __launch_bounds__(256) void gather_msg(
    const unsigned* __restrict__ node_bf, const float2* __restrict__ rel2,
    const int* __restrict__ offs, const int2* __restrict__ sortedp,
    unsigned* __restrict__ meanbf, int t)
{
    int n = blockIdx.x * 4 + (threadIdx.x >> 6);
    int lane = threadIdx.x & 63;
    if (n >= N_ENT) return;
    const int* op = offs + (size_t)t * N_PAD;
    int end = op[n];
    int start = (n > 0) ? op[n - 1] : 0;
    int deg = end - start;
    if (deg == 0) return;
    const int2* sp = sortedp + (size_t)t * E_EDGES;
    float ax = 0.f, ay = 0.f;
    for (int p = start; p < end; ++p) {
        int2 pr = sp[p];
        unsigned nb = node_bf[(size_t)pr.x * 64 + lane];
        float2 rv = rel2[pr.y * 64 + lane];
        ax += bf_lo(nb) * rv.x;
        ay += bf_hi(nb) * rv.y;
    }
    float inv = 1.0f / (float)deg;
    meanbf[(size_t)n * 64 + lane] = pk2(ax * inv, ay * inv);
}

// ---------------- per-step: node += mean for active nodes only ----------------
__global__ __launch_bounds__(256) void update_kernel(
    unsigned* __restrict__ node_bf, const unsigned* __restrict__ meanbf,
    const int* __restrict__ offs, int t)
{
    int n = blockIdx.x * 4 + (threadIdx.x >> 6);
    int lane = threadIdx.x & 63;
    if (n >= N_ENT) return;
    const int* op = offs + (size_t)t * N_PAD;
    int end = op[n];
    int start = (n > 0) ? op[n - 1] : 0;
    if (end == start) return;
    size_t idx = (size_t)n * 64 + lane;
    unsigned nb = node_bf[idx];
    unsigned mb = meanbf[idx];
    node_bf[idx] = pk2(bf_lo(nb) + bf_lo(mb), bf_hi(nb) + bf_hi(mb));
}

// ---------------- per-step: snapshot seed rows into gathered[tt][4-j] (fp32) ----------------
__global__ __launch_bounds__(256) void gather_seed(
    const unsigned* __restrict__ node_bf, const int* __restrict__ seeds,
    float2* __restrict__ gath2, int t)
{
    int gid = blockIdx.x * 256 + threadIdx.x;   // 5*256*64 = 81920 threads
    int j = gid >> 14;
    int tt = t + j;
    if (tt >= T_STEPS) return;
    int rem = gid & 16383;
    int s = rem >> 6;
    int lane = rem & 63;
    int w = 4 - j;
    int node = seeds[tt * S_SEEDS + s];
    unsigned nb = node_bf[(size_t)node * 64 + lane];
    gath2[((tt * 5 + w) * S_SEEDS + s) * 64 + lane] = make_float2(bf_lo(nb), bf_hi(nb));
}

// ---------------- 5-snapshot attention per (t,s): one wave each; writes u fp32 + bf16 ----------------
__global__ __launch_bounds__(64) void attn_kernel(
    const float2* __restrict__ q2, const float2* __restrict__ g2,
    const int* __restrict__ seeds, float2* __restrict__ u2, unsigned* __restrict__ ubf)
{
    int b = blockIdx.x;          // 4096 = T*S
    int t = b >> 8;
    int s = b & 255;
    int lane = threadIdx.x;
    int seed = seeds[t * S_SEEDS + s];
    float2 q = q2[seed * 64 + lane];
    float2 g[5];
    float att[5];
    #pragma unroll
    for (int w = 0; w < 5; ++w) {
        float2 gv = g2[((t * 5 + w) * S_SEEDS + s) * 64 + lane];
        g[w] = gv;
        float p = gv.x * q.x + gv.y * q.y;
        #pragma unroll
        for (int off = 32; off > 0; off >>= 1) p += __shfl_xor(p, off, 64);
        att[w] = (w >= 4 - t) ? p : -1e9f;   // invalid slots masked -> weight exactly 0
    }
    float m = -1e30f;
    #pragma unroll
    for (int w = 0; w < 5; ++w) m = fmaxf(m, att[w]);
    float den = 0.f;
    #pragma unroll
    for (int w = 0; w < 5; ++w) den += __expf(att[w] - m);
    float invd = 1.0f / den;
    float2 o = make_float2(0.f, 0.f);
    #pragma unroll
    for (int w = 0; w < 5; ++w) {
        float wt = __expf(att[w] - m) * invd;
        o.x += wt * g[w].x;
        o.y += wt * g[w].y;
    }
    int idx = (t * S_SEEDS + s) * 64 + lane;
    u2[idx] = o;
    ubf[idx] = pk2(o.x, o.y);
}

// ---------------- MFMA score GEMM + streaming sum(exp) ----------------
__global__ __launch_bounds__(256) void score_mfma(
    const unsigned short* __restrict__ ub, const unsigned short* __restrict__ cb,
    float* __restrict__ rowsum)
{
    int tid = threadIdx.x;
    int wv = tid >> 6, lane = tid & 63;
    int col16 = lane & 15, quad = lane >> 4;
    int rb = blockIdx.x;                 // 64 row-blocks of 64 rows
    int j = blockIdx.y * 4 + wv;         // wave slice 0..31

    short8 a[4][4];
    #pragma unroll
    for (int g = 0; g < 4; ++g) {
        const unsigned short* ap = ub + (size_t)(rb * 64 + g * 16 + col16) * DD + quad * 8;
        #pragma unroll
        for (int kk = 0; kk < 4; ++kk)
            a[g][kk] = *(const short8*)(ap + kk * 32);
    }

    float es[4][4];
    #pragma unroll
    for (int g = 0; g < 4; ++g)
        #pragma unroll
        for (int r = 0; r < 4; ++r) es[g][r] = 0.f;

    for (int c = j; c < 3125; c += 32) {
        const unsigned short* bp = cb + (size_t)(c * 16 + col16) * DD + quad * 8;
        short8 b0 = *(const short8*)(bp);
        short8 b1 = *(const short8*)(bp + 32);
        short8 b2 = *(const short8*)(bp + 64);
        short8 b3 = *(const short8*)(bp + 96);
        #pragma unroll
        for (int g = 0; g < 4; ++g) {
            f32x4 d = {0.f, 0.f, 0.f, 0.f};
            d = __builtin_amdgcn_mfma_f32_16x16x32_bf16(a[g][0], b0, d, 0, 0, 0);
            d = __builtin_amdgcn_mfma_f32_16x16x32_bf16(a[g][1], b1, d, 0, 0, 0);
            d = __builtin_amdgcn_mfma_f32_16x16x32_bf16(a[g][2], b2, d, 0, 0, 0);
            d = __builtin_amdgcn_mfma_f32_16x16x32_bf16(a[g][3], b3, d, 0, 0, 0);
            #pragma unroll
            for (int r = 0; r < 4; ++r) es[g][r] += __expf(d[r]);
        }
    }

    #pragma unroll
    for (int g = 0; g < 4; ++g) {
        #pragma unroll
        for (int r = 0; r < 4; ++r) {
            float v = es[g][r];
            v += __shfl_xor(v, 1, 64);
            v += __shfl_xor(v, 2, 64);
            v += __shfl_xor(v, 4, 64);
            v += __shfl_xor(v, 8, 64);
            if (col16 == 0)
                atomicAdd(&rowsum[rb * 64 + g * 16 + quad * 4 + r], v);
        }
    }
}

// ---------------- final: loss = sum(log(rowsum) - pos), pos in fp32 ----------------
__global__ __launch_bounds__(256) void final_kernel(
    const float2* __restrict__ u2, const float* __restrict__ ent,
    const int* __restrict__ cidx, const float* __restrict__ rowsum,
    float* __restrict__ out)
{
    int wv = threadIdx.x >> 6, lane = threadIdx.x & 63;
    int row = blockIdx.x * 4 + wv;       // grid 1024 -> 4096 rows
    int ci = cidx[row];
    const float2* tp = (const float2*)(ent + (size_t)(BASE + ci) * DD);
    float2 a = u2[row * 64 + lane];
    float2 t = tp[lane];
    float p = a.x * t.x + a.y * t.y;
    #pragma unroll
    for (int off = 32; off > 0; off >>= 1) p += __shfl_xor(p, off, 64);
    if (lane == 0) atomicAdd(out, logf(rowsum[row]) - p);
}

extern "C" void kernel_launch(void* const* d_in, const int* in_sizes, int n_in,
                              void* d_out, int out_size, void* d_ws, size_t ws_size,
                              hipStream_t stream)
{
    (void)in_sizes; (void)n_in; (void)out_size; (void)ws_size;
    const float* ent   = (const float*)d_in[0];
    const float* query = (const float*)d_in[1];
    const float* rel   = (const float*)d_in[2];
    const int* esrc    = (const int*)d_in[3];
    const int* edst    = (const int*)d_in[4];
    const int* erel    = (const int*)d_in[5];
    const int* seeds   = (const int*)d_in[6];
    const int* cidx    = (const int*)d_in[7];
    float* out = (float*)d_out;

    // ws layout: node_bf | meanbf | offs(padded) | partials | sortedp | gath | u | ubf | cb | rowsum
    char* ws = (char*)d_ws;
    size_t off = 0;
    unsigned* node_bf = (unsigned*)(ws + off);       off += (size_t)N_ENT * DD * 2;          // 64.0 MB
    unsigned* meanbf  = (unsigned*)(ws + off);       off += (size_t)N_ENT * DD * 2;          // 64.0 MB
    int*      offs    = (int*)(ws + off);            off += (size_t)T_STEPS * N_PAD * 4;     // 16.1 MB
    int*      partials= (int*)(ws + off);            off += (size_t)T_STEPS * NB * 4;        // 15.7 KB
    int2*     sortedp = (int2*)(ws + off);           off += (size_t)T_STEPS * E_EDGES * 8;   // 38.4 MB
    float*    gath    = (float*)(ws + off);          off += (size_t)T_STEPS * 5 * S_SEEDS * DD * 4;
    float*    u       = (float*)(ws + off);          off += (size_t)T_STEPS * S_SEEDS * DD * 4;
    unsigned* ubf     = (unsigned*)(ws + off);       off += (size_t)T_STEPS * S_SEEDS * DD * 2;
    unsigned short* cb = (unsigned short*)(ws + off); off += (size_t)C_NUM * DD * 2;
    float*    rsum    = (float*)(ws + off);          off += (size_t)T_STEPS * S_SEEDS * 4;

    int init_items = NODE_W + OFFS_W + T_STEPS * S_SEEDS + 1;
    init_kernel<<<(init_items + 255) / 256, 256, 0, stream>>>(
        (const float2*)ent, node_bf, offs, rsum, out);
    conv_kernel<<<C_NUM * DD / 4 / 256, 256, 0, stream>>>(
        (const float4*)(ent + (size_t)BASE * DD), (ushort4*)cb);

    dim3 egrid((E_EDGES + 255) / 256, T_STEPS);
    dim3 sgrid(NB, T_STEPS);
    hist_kernel<<<egrid, 256, 0, stream>>>(edst, offs);
    scanA_kernel<<<sgrid, 256, 0, stream>>>(offs, partials);
    scanB_kernel<<<T_STEPS, 256, 0, stream>>>(partials);
    scanC_kernel<<<sgrid, 256, 0, stream>>>(offs, partials);
    scatp_kernel<<<egrid, 256, 0, stream>>>(esrc, edst, erel, offs, sortedp);

    int ngrid = (N_ENT + 3) / 4;
    for (int t = 0; t < T_STEPS; ++t) {
        gather_msg<<<ngrid, 256, 0, stream>>>(
            node_bf, (const float2*)rel, offs, sortedp, meanbf, t);
        update_kernel<<<ngrid, 256, 0, stream>>>(node_bf, meanbf, offs, t);
        gather_seed<<<5 * S_SEEDS * 64 / 256, 256, 0, stream>>>(
            node_bf, seeds, (float2*)gath, t);
    }
    attn_kernel<<<T_STEPS * S_SEEDS, 64, 0, stream>>>(
        (const float2*)query, (const float2*)gath, seeds, (float2*)u, (unsigned*)ubf);
    score_mfma<<<dim3(64, 8), 256, 0, stream>>>((const unsigned short*)ubf, cb, rsum);
    final_kernel<<<T_STEPS * S_SEEDS / 4, 256, 0, stream>>>(
        (const float2*)u, ent, cidx, rsum, out);
}